// Round 2
// baseline (2207.184 us; speedup 1.0000x reference)
//
#include <hip/hip_runtime.h>
#include <math.h>

#define B_ 4
#define L_ 1024
#define IN_DIM_ 46
#define D_ 256
#define DS_ 64
#define K_ 4
#define NL_ 4
#define DI_ 512
#define HD_ 64
#define H_ 8
#define XBC_ 640
#define DIP_ 1160
#define DFF_ 512
#define AH_ 4
#define AHD_ 64
#define NT_ (B_*L_)
#define QKVD_ (3*D_)

// ---------- helpers ----------
__device__ __forceinline__ float block_sum_256(float v) {
    __shared__ float sb[4];
    #pragma unroll
    for (int off = 32; off > 0; off >>= 1) v += __shfl_down(v, off, 64);
    int lane = threadIdx.x & 63, wid = threadIdx.x >> 6;
    if (lane == 0) sb[wid] = v;
    __syncthreads();
    float r = sb[0] + sb[1] + sb[2] + sb[3];
    __syncthreads();
    return r;
}

__device__ __forceinline__ float siluf(float x) { return x / (1.f + expf(-x)); }
__device__ __forceinline__ float softplusf(float x) {
    return (x > 20.f) ? x : log1pf(expf(x));
}

// ---------- K1: h = x @ in_w + in_b + pos ----------
__global__ __launch_bounds__(256) void in_proj_kernel(
        const float* __restrict__ x, const float* __restrict__ in_w,
        const float* __restrict__ in_b, const float* __restrict__ pos,
        float* __restrict__ Hb) {
    int t = blockIdx.x, tid = threadIdx.x;
    int l = t % L_;
    __shared__ float xs[IN_DIM_];
    if (tid < IN_DIM_) xs[tid] = x[(size_t)t * IN_DIM_ + tid];
    __syncthreads();
    float acc = in_b[tid] + pos[(size_t)l * D_ + tid];
    #pragma unroll 2
    for (int c = 0; c < IN_DIM_; ++c) acc += xs[c] * in_w[c * D_ + tid];
    Hb[(size_t)t * D_ + tid] = acc;
}

// ---------- K2: LayerNorm over D=256 ----------
__global__ __launch_bounds__(256) void ln_kernel(
        const float* __restrict__ in, const float* __restrict__ w,
        const float* __restrict__ b, float* __restrict__ out) {
    int r = blockIdx.x, tid = threadIdx.x;
    float v = in[(size_t)r * D_ + tid];
    float mean = block_sum_256(v) * (1.f / D_);
    float c = v - mean;
    float var = block_sum_256(c * c) * (1.f / D_);
    out[(size_t)r * D_ + tid] = c * rsqrtf(var + 1e-5f) * w[tid] + b[tid];
}

// ---------- K3: tiled fp32 GEMM C[M,N] = A[M,K] @ W[K,N] (+bias)(+res) ----------
// 64x64 tile, K-step 32 (16.5 KB LDS), 4x4 acc per thread.
template<bool BIAS, bool RES>
__global__ __launch_bounds__(256) void gemm64(
        const float* __restrict__ A, const float* __restrict__ W,
        const float* __restrict__ bias, const float* __restrict__ res,
        float* __restrict__ C, int M, int N, int Kd) {
    __shared__ float As[32][65];
    __shared__ float Ws[32][64];
    int tid = threadIdx.x;
    int tx = tid & 15, ty = tid >> 4;
    int n0 = blockIdx.x * 64, m0 = blockIdx.y * 64;
    float acc[4][4] = {};
    for (int k0 = 0; k0 < Kd; k0 += 32) {
        // A tile: 64 m x 32 k, k fastest for coalescing
        {
            int k = tid & 31, m = tid >> 5;   // m 0..7; 8 iters cover 64 rows
            #pragma unroll
            for (int i = 0; i < 8; ++i) {
                int mm = m + i * 8;
                As[k][mm] = A[(size_t)(m0 + mm) * Kd + k0 + k];
            }
        }
        // W tile: 32 k x 64 n, n fastest
        #pragma unroll
        for (int i = 0; i < 8; ++i) {
            int idx = tid + i * 256;
            int k = idx >> 6, n = idx & 63;
            int nn = n0 + n;
            Ws[k][n] = (nn < N) ? W[(size_t)(k0 + k) * N + nn] : 0.f;
        }
        __syncthreads();
        #pragma unroll
        for (int k = 0; k < 32; ++k) {
            float a[4], bb[4];
            #pragma unroll
            for (int i = 0; i < 4; ++i) a[i] = As[k][ty * 4 + i];
            #pragma unroll
            for (int j = 0; j < 4; ++j) bb[j] = Ws[k][tx * 4 + j];
            #pragma unroll
            for (int i = 0; i < 4; ++i)
                #pragma unroll
                for (int j = 0; j < 4; ++j) acc[i][j] += a[i] * bb[j];
        }
        __syncthreads();
    }
    #pragma unroll
    for (int i = 0; i < 4; ++i) {
        int m = m0 + ty * 4 + i;
        #pragma unroll
        for (int j = 0; j < 4; ++j) {
            int n = n0 + tx * 4 + j;
            if (n < N) {
                float v = acc[i][j];
                if (BIAS) v += bias[n];
                if (RES) v += res[(size_t)m * N + n];
                C[(size_t)m * N + n] = v;
            }
        }
    }
}

// ---------- K4: causal conv K=4 + bias + silu over xBC channels ----------
__global__ __launch_bounds__(256) void conv_kernel(
        const float* __restrict__ ZX, const float* __restrict__ cw,
        const float* __restrict__ cb, float* __restrict__ XC) {
    int idx = blockIdx.x * 256 + threadIdx.x;
    if (idx >= NT_ * XBC_) return;
    int c = idx % XBC_;
    int t = idx / XBC_;
    int l = t % L_;
    float acc = cb[c];
    #pragma unroll
    for (int k = 0; k < K_; ++k) {
        int lp = l + k - (K_ - 1);
        if (lp >= 0)
            acc += ZX[(size_t)(t + k - (K_ - 1)) * DIP_ + DI_ + c] * cw[k * XBC_ + c];
    }
    XC[(size_t)idx] = siluf(acc);
}

// ---------- K5: dt softplus + a + cumsum(cA) per (b,h) ----------
__global__ __launch_bounds__(256) void dt_cumsum_kernel(
        const float* __restrict__ ZX, const float* __restrict__ dt_bias,
        const float* __restrict__ A_log, float* __restrict__ DT,
        float* __restrict__ CA) {
    int b = blockIdx.x / H_, h = blockIdx.x % H_;
    int tid = threadIdx.x;
    __shared__ float sc[256];
    float nA = -expf(A_log[h]);
    float bias = dt_bias[h];
    float carry = 0.f;
    for (int chunk = 0; chunk < L_ / 256; ++chunk) {
        int l = chunk * 256 + tid;
        size_t t = (size_t)b * L_ + l;
        float xv = ZX[t * DIP_ + DI_ + XBC_ + h] + bias;
        float dts = softplusf(xv);
        DT[t * H_ + h] = dts;
        float a = dts * nA;
        sc[tid] = a;
        __syncthreads();
        float v = a;
        for (int off = 1; off < 256; off <<= 1) {
            float add = (tid >= off) ? sc[tid - off] : 0.f;
            __syncthreads();
            v += add;
            sc[tid] = v;
            __syncthreads();
        }
        CA[t * H_ + h] = carry + v;
        carry += sc[255];
        __syncthreads();
    }
}

// ---------- K6: CB[b,t,s] = Cm[b,t,:] . Bm[b,s,:], causal tiles ----------
__global__ __launch_bounds__(256) void cb_kernel(
        const float* __restrict__ XC, float* __restrict__ CB) {
    int b = blockIdx.z;
    int t0 = blockIdx.y * 64, s0 = blockIdx.x * 64;
    if (s0 > t0 + 63) return;
    __shared__ float Cs[64][65], Bs[64][65];
    int tid = threadIdx.x, tx = tid & 15, ty = tid >> 4;
    #pragma unroll
    for (int i = 0; i < 16; ++i) {
        int idx = tid + i * 256;
        int rr = idx >> 6, cc = idx & 63;
        Cs[rr][cc] = XC[(size_t)(b * L_ + t0 + rr) * XBC_ + DI_ + DS_ + cc];
        Bs[rr][cc] = XC[(size_t)(b * L_ + s0 + rr) * XBC_ + DI_ + cc];
    }
    __syncthreads();
    float acc[4][4] = {};
    for (int n = 0; n < 64; ++n) {
        float a[4], bb[4];
        #pragma unroll
        for (int i = 0; i < 4; ++i) a[i] = Cs[ty * 4 + i][n];
        #pragma unroll
        for (int j = 0; j < 4; ++j) bb[j] = Bs[tx * 4 + j][n];
        #pragma unroll
        for (int i = 0; i < 4; ++i)
            #pragma unroll
            for (int j = 0; j < 4; ++j) acc[i][j] += a[i] * bb[j];
    }
    #pragma unroll
    for (int i = 0; i < 4; ++i) {
        int t = t0 + ty * 4 + i;
        #pragma unroll
        for (int j = 0; j < 4; ++j) {
            int s = s0 + tx * 4 + j;
            CB[((size_t)b * L_ + t) * L_ + s] = acc[i][j];
        }
    }
}

// ---------- K7: SSM quadratic y[t,p] = sum_{s<=t} exp(cA_t-cA_s)*CB*dt_s*x[s,p] + D*x[t,p] ----------
__global__ __launch_bounds__(256) void ssm_quad_kernel(
        const float* __restrict__ XC, const float* __restrict__ CB,
        const float* __restrict__ DT, const float* __restrict__ CA,
        const float* __restrict__ Dh_ptr, float* __restrict__ Y) {
    int b = blockIdx.z, h = blockIdx.y;
    int t0 = blockIdx.x * 64;
    int tid = threadIdx.x, tx = tid & 15, ty = tid >> 4;
    __shared__ float P[64][65], Xs[64][65];
    __shared__ float cat[64], cas[64], dts[64];
    if (tid < 64) cat[tid] = CA[((size_t)b * L_ + t0 + tid) * H_ + h];
    float acc[4][4] = {};
    float Dh = Dh_ptr[h];
    for (int s0 = 0; s0 <= t0; s0 += 64) {
        #pragma unroll
        for (int i = 0; i < 16; ++i) {
            int idx = tid + i * 256;
            int rr = idx >> 6, cc = idx & 63;
            Xs[rr][cc] = XC[(size_t)(b * L_ + s0 + rr) * XBC_ + h * HD_ + cc];
        }
        if (tid < 64) {
            cas[tid] = CA[((size_t)b * L_ + s0 + tid) * H_ + h];
            dts[tid] = DT[((size_t)b * L_ + s0 + tid) * H_ + h];
        }
        __syncthreads();
        #pragma unroll
        for (int i = 0; i < 4; ++i) {
            int t = ty * 4 + i;
            float ct = cat[t];
            #pragma unroll
            for (int j = 0; j < 4; ++j) {
                int s = tx * 4 + j;
                float v = 0.f;
                if (s0 + s <= t0 + t) {
                    float cb = CB[((size_t)b * L_ + t0 + t) * L_ + s0 + s];
                    v = expf(ct - cas[s]) * cb * dts[s];
                }
                P[t][s] = v;
            }
        }
        __syncthreads();
        for (int s = 0; s < 64; ++s) {
            float a[4], xv[4];
            #pragma unroll
            for (int i = 0; i < 4; ++i) a[i] = P[ty * 4 + i][s];
            #pragma unroll
            for (int j = 0; j < 4; ++j) xv[j] = Xs[s][tx * 4 + j];
            #pragma unroll
            for (int i = 0; i < 4; ++i)
                #pragma unroll
                for (int j = 0; j < 4; ++j) acc[i][j] += a[i] * xv[j];
        }
        __syncthreads();
    }
    #pragma unroll
    for (int i = 0; i < 4; ++i) {
        size_t t = (size_t)b * L_ + t0 + ty * 4 + i;
        #pragma unroll
        for (int j = 0; j < 4; ++j) {
            int p = tx * 4 + j;
            float x4 = XC[t * XBC_ + h * HD_ + p];
            Y[t * DI_ + h * HD_ + p] = acc[i][j] + Dh * x4;
        }
    }
}

// ---------- K8: y = y*silu(z); RMSNorm(DI) * nw  (in-place on Y) ----------
__global__ __launch_bounds__(256) void gate_rms_kernel(
        float* __restrict__ Y, const float* __restrict__ ZX,
        const float* __restrict__ nw) {
    int r = blockIdx.x, tid = threadIdx.x;
    size_t ry = (size_t)r * DI_, rz = (size_t)r * DIP_;
    float y0 = Y[ry + tid], y1 = Y[ry + 256 + tid];
    float z0 = ZX[rz + tid], z1 = ZX[rz + 256 + tid];
    y0 *= siluf(z0);
    y1 *= siluf(z1);
    float ss = block_sum_256(y0 * y0 + y1 * y1) * (1.f / DI_);
    float s = rsqrtf(ss + 1e-5f);
    Y[ry + tid] = y0 * s * nw[tid];
    Y[ry + 256 + tid] = y1 * s * nw[256 + tid];
}

// ---------- K9: flash attention (non-causal), head dim 64 ----------
__global__ __launch_bounds__(256) void attn_kernel(
        const float* __restrict__ QKV, float* __restrict__ O) {
    int b = blockIdx.z, hh = blockIdx.y;
    int t0 = blockIdx.x * 64;
    int tid = threadIdx.x, tx = tid & 15, ty = tid >> 4;
    __shared__ float Qs[64][65], Ks[64][65], Vs[64][65];
    #pragma unroll
    for (int i = 0; i < 16; ++i) {
        int idx = tid + i * 256;
        int rr = idx >> 6, cc = idx & 63;
        Qs[rr][cc] = QKV[(size_t)(b * L_ + t0 + rr) * QKVD_ + hh * AHD_ + cc];
    }
    float m[4], lsum[4], acc[4][4] = {};
    #pragma unroll
    for (int i = 0; i < 4; ++i) { m[i] = -INFINITY; lsum[i] = 0.f; }
    for (int s0 = 0; s0 < L_; s0 += 64) {
        #pragma unroll
        for (int i = 0; i < 16; ++i) {
            int idx = tid + i * 256;
            int rr = idx >> 6, cc = idx & 63;
            Ks[rr][cc] = QKV[(size_t)(b * L_ + s0 + rr) * QKVD_ + D_ + hh * AHD_ + cc];
            Vs[rr][cc] = QKV[(size_t)(b * L_ + s0 + rr) * QKVD_ + 2 * D_ + hh * AHD_ + cc];
        }
        __syncthreads();
        float sv[4][4];
        #pragma unroll
        for (int i = 0; i < 4; ++i)
            #pragma unroll
            for (int j = 0; j < 4; ++j) sv[i][j] = 0.f;
        for (int d = 0; d < 64; ++d) {
            float a[4], kk[4];
            #pragma unroll
            for (int i = 0; i < 4; ++i) a[i] = Qs[ty * 4 + i][d];
            #pragma unroll
            for (int j = 0; j < 4; ++j) kk[j] = Ks[tx * 4 + j][d];
            #pragma unroll
            for (int i = 0; i < 4; ++i)
                #pragma unroll
                for (int j = 0; j < 4; ++j) sv[i][j] += a[i] * kk[j];
        }
        __syncthreads();   // done reading K
        #pragma unroll
        for (int i = 0; i < 4; ++i)
            #pragma unroll
            for (int j = 0; j < 4; ++j) Ks[ty * 4 + i][tx * 4 + j] = sv[i][j] * 0.125f;
        __syncthreads();   // all S visible
        float newm[4], corr[4];
        #pragma unroll
        for (int i = 0; i < 4; ++i) {
            int t = ty * 4 + i;
            float mx = m[i];
            for (int s = 0; s < 64; ++s) mx = fmaxf(mx, Ks[t][s]);
            newm[i] = mx; corr[i] = expf(m[i] - mx); m[i] = mx;
        }
        __syncthreads();   // done reading S
        #pragma unroll
        for (int i = 0; i < 4; ++i)
            #pragma unroll
            for (int j = 0; j < 4; ++j)
                Ks[ty * 4 + i][tx * 4 + j] = expf(sv[i][j] * 0.125f - newm[i]);
        __syncthreads();   // all P visible
        #pragma unroll
        for (int i = 0; i < 4; ++i) {
            int t = ty * 4 + i;
            float sm = 0.f;
            for (int s = 0; s < 64; ++s) sm += Ks[t][s];
            lsum[i] = lsum[i] * corr[i] + sm;
        }
        #pragma unroll
        for (int i = 0; i < 4; ++i)
            #pragma unroll
            for (int j = 0; j < 4; ++j) acc[i][j] *= corr[i];
        for (int s = 0; s < 64; ++s) {
            float a[4], vv[4];
            #pragma unroll
            for (int i = 0; i < 4; ++i) a[i] = Ks[ty * 4 + i][s];
            #pragma unroll
            for (int j = 0; j < 4; ++j) vv[j] = Vs[s][tx * 4 + j];
            #pragma unroll
            for (int i = 0; i < 4; ++i)
                #pragma unroll
                for (int j = 0; j < 4; ++j) acc[i][j] += a[i] * vv[j];
        }
        __syncthreads();   // before next tile overwrites Ks/Vs
    }
    #pragma unroll
    for (int i = 0; i < 4; ++i) {
        size_t t = (size_t)b * L_ + t0 + ty * 4 + i;
        #pragma unroll
        for (int j = 0; j < 4; ++j)
            O[t * D_ + hh * AHD_ + tx * 4 + j] = acc[i][j] / lsum[i];
    }
}

// ---------- K10: GEGLU ----------
__global__ __launch_bounds__(256) void geglu_kernel(
        const float* __restrict__ M1, float* __restrict__ M2) {
    int idx = blockIdx.x * 256 + threadIdx.x;
    if (idx >= NT_ * DFF_) return;
    int r = idx / DFF_, c = idx % DFF_;
    float x1 = M1[(size_t)r * (2 * DFF_) + c];
    float x2 = M1[(size_t)r * (2 * DFF_) + DFF_ + c];
    float g = 0.5f * x1 * (1.f + erff(x1 * 0.70710678118f));
    M2[(size_t)idx] = g * x2;
}

// ---------- K11: mean over L + two linear heads ----------
__global__ __launch_bounds__(256) void head_kernel(
        const float* __restrict__ LN, const float* __restrict__ dir_w,
        const float* __restrict__ dir_b, const float* __restrict__ reg_w,
        const float* __restrict__ reg_b, float* __restrict__ out) {
    int b = blockIdx.x, tid = threadIdx.x;
    __shared__ float hm[256];
    float s = 0.f;
    for (int l = 0; l < L_; ++l) s += LN[(size_t)(b * L_ + l) * D_ + tid];
    hm[tid] = s * (1.f / L_);
    __syncthreads();
    if (tid < 6) {
        const float* w = (tid < 3) ? dir_w : reg_w;
        const float* bb = (tid < 3) ? dir_b : reg_b;
        int j = (tid < 3) ? tid : tid - 3;
        float acc = bb[j];
        for (int d = 0; d < 256; ++d) acc += hm[d] * w[d * 3 + j];
        out[((tid < 3) ? 0 : 12) + b * 3 + j] = acc;
    }
}

// ---------- host ----------
static inline int cdiv(int a, int b) { return (a + b - 1) / b; }

extern "C" void kernel_launch(void* const* d_in, const int* in_sizes, int n_in,
                              void* d_out, int out_size, void* d_ws, size_t ws_size,
                              hipStream_t stream) {
    const float* x          = (const float*)d_in[0];
    const float* pos_emb    = (const float*)d_in[1];
    const float* in_w       = (const float*)d_in[2];
    const float* in_b       = (const float*)d_in[3];
    const float* ln1_w      = (const float*)d_in[4];
    const float* ln1_b      = (const float*)d_in[5];
    const float* ssm_in_w   = (const float*)d_in[6];
    const float* ssm_conv_w = (const float*)d_in[7];
    const float* ssm_conv_b = (const float*)d_in[8];
    const float* ssm_dt_bias= (const float*)d_in[9];
    const float* ssm_A_log  = (const float*)d_in[10];
    const float* ssm_Dp     = (const float*)d_in[11];
    const float* ssm_norm_w = (const float*)d_in[12];
    const float* ssm_out_w  = (const float*)d_in[13];
    const float* ln2_w      = (const float*)d_in[14];
    const float* ln2_b      = (const float*)d_in[15];
    const float* fc1_w      = (const float*)d_in[16];
    const float* fc1_b      = (const float*)d_in[17];
    const float* fc2_w      = (const float*)d_in[18];
    const float* fc2_b      = (const float*)d_in[19];
    const float* attn_ln_w  = (const float*)d_in[20];
    const float* attn_ln_b  = (const float*)d_in[21];
    const float* attn_qkv_w = (const float*)d_in[22];
    const float* attn_qkv_b = (const float*)d_in[23];
    const float* attn_out_w = (const float*)d_in[24];
    const float* attn_out_b = (const float*)d_in[25];
    const float* norm_w     = (const float*)d_in[26];
    const float* norm_b     = (const float*)d_in[27];
    const float* dir_w      = (const float*)d_in[28];
    const float* dir_b      = (const float*)d_in[29];
    const float* reg_w      = (const float*)d_in[30];
    const float* reg_b      = (const float*)d_in[31];
    float* out = (float*)d_out;
    float* ws  = (float*)d_ws;

    size_t off = 0;
    float* Hb  = ws + off; off += (size_t)NT_ * D_;     // h
    float* LN  = ws + off; off += (size_t)NT_ * D_;     // ln output
    float* ZX  = ws + off; off += (size_t)NT_ * DIP_;   // zxbcdt / qkv / mlp1 (aliased)
    float* XC  = ws + off; off += (size_t)NT_ * XBC_;   // conv out / attn out / mlp2 (aliased)
    float* DTb = ws + off; off += (size_t)NT_ * H_;
    float* CAb = ws + off; off += (size_t)NT_ * H_;
    float* CBb = ws + off; off += (size_t)B_ * L_ * L_;
    float* Yb  = ws + off; off += (size_t)NT_ * DI_;

    dim3 blk(256);

    // input projection
    in_proj_kernel<<<NT_, blk, 0, stream>>>(x, in_w, in_b, pos_emb, Hb);

    for (int i = 0; i < NL_; ++i) {
        // ---- Mamba2 block ----
        ln_kernel<<<NT_, blk, 0, stream>>>(Hb, ln1_w + i * D_, ln1_b + i * D_, LN);
        gemm64<false,false><<<dim3(cdiv(DIP_,64), NT_/64), blk, 0, stream>>>(
            LN, ssm_in_w + (size_t)i * D_ * DIP_, nullptr, nullptr, ZX, NT_, DIP_, D_);
        conv_kernel<<<cdiv(NT_*XBC_,256), blk, 0, stream>>>(
            ZX, ssm_conv_w + (size_t)i * K_ * XBC_, ssm_conv_b + i * XBC_, XC);
        dt_cumsum_kernel<<<B_*H_, blk, 0, stream>>>(
            ZX, ssm_dt_bias + i * H_, ssm_A_log + i * H_, DTb, CAb);
        cb_kernel<<<dim3(L_/64, L_/64, B_), blk, 0, stream>>>(XC, CBb);
        ssm_quad_kernel<<<dim3(L_/64, H_, B_), blk, 0, stream>>>(
            XC, CBb, DTb, CAb, ssm_Dp + i * H_, Yb);
        gate_rms_kernel<<<NT_, blk, 0, stream>>>(Yb, ZX, ssm_norm_w + (size_t)i * DI_);
        gemm64<false,true><<<dim3(cdiv(D_,64), NT_/64), blk, 0, stream>>>(
            Yb, ssm_out_w + (size_t)i * DI_ * D_, nullptr, Hb, Hb, NT_, D_, DI_);

        // ---- attention (odd layers) ----
        if (i % 2 == 1) {
            int j = i / 2;
            ln_kernel<<<NT_, blk, 0, stream>>>(Hb, attn_ln_w + j * D_, attn_ln_b + j * D_, LN);
            gemm64<true,false><<<dim3(cdiv(QKVD_,64), NT_/64), blk, 0, stream>>>(
                LN, attn_qkv_w + (size_t)j * D_ * QKVD_, attn_qkv_b + j * QKVD_,
                nullptr, ZX, NT_, QKVD_, D_);
            attn_kernel<<<dim3(L_/64, AH_, B_), blk, 0, stream>>>(ZX, XC);
            gemm64<true,true><<<dim3(cdiv(D_,64), NT_/64), blk, 0, stream>>>(
                XC, attn_out_w + (size_t)j * D_ * D_, attn_out_b + j * D_,
                Hb, Hb, NT_, D_, D_);
        }

        // ---- gated MLP ----
        ln_kernel<<<NT_, blk, 0, stream>>>(Hb, ln2_w + i * D_, ln2_b + i * D_, LN);
        gemm64<true,false><<<dim3(cdiv(2*DFF_,64), NT_/64), blk, 0, stream>>>(
            LN, fc1_w + (size_t)i * D_ * 2 * DFF_, fc1_b + i * 2 * DFF_,
            nullptr, ZX, NT_, 2 * DFF_, D_);
        geglu_kernel<<<cdiv(NT_*DFF_,256), blk, 0, stream>>>(ZX, XC);
        gemm64<true,true><<<dim3(cdiv(D_,64), NT_/64), blk, 0, stream>>>(
            XC, fc2_w + (size_t)i * DFF_ * D_, fc2_b + i * D_,
            Hb, Hb, NT_, D_, DFF_);
    }

    // final norm + mean + heads
    ln_kernel<<<NT_, blk, 0, stream>>>(Hb, norm_w, norm_b, LN);
    head_kernel<<<B_, blk, 0, stream>>>(LN, dir_w, dir_b, reg_w, reg_b, out);
}

// Round 6
// 1561.923 us; speedup vs baseline: 1.4131x; 1.4131x over previous
//
#include <hip/hip_runtime.h>
#include <math.h>

#define B_ 4
#define L_ 1024
#define IN_DIM_ 46
#define D_ 256
#define DS_ 64
#define K_ 4
#define NL_ 4
#define DI_ 512
#define HD_ 64
#define H_ 8
#define XBC_ 640
#define DIP_ 1160
#define DFF_ 512
#define AH_ 4
#define AHD_ 64
#define NT_ (B_*L_)
#define QKVD_ (3*D_)

// ---------- helpers ----------
__device__ __forceinline__ float block_sum_256(float v) {
    __shared__ float sb[4];
    #pragma unroll
    for (int off = 32; off > 0; off >>= 1) v += __shfl_down(v, off, 64);
    int lane = threadIdx.x & 63, wid = threadIdx.x >> 6;
    if (lane == 0) sb[wid] = v;
    __syncthreads();
    float r = sb[0] + sb[1] + sb[2] + sb[3];
    __syncthreads();
    return r;
}

__device__ __forceinline__ float siluf(float x) { return x / (1.f + expf(-x)); }
__device__ __forceinline__ float softplusf(float x) {
    return (x > 20.f) ? x : log1pf(expf(x));
}

// ---------- K1: h = x @ in_w + in_b + pos ----------
__global__ __launch_bounds__(256) void in_proj_kernel(
        const float* __restrict__ x, const float* __restrict__ in_w,
        const float* __restrict__ in_b, const float* __restrict__ pos,
        float* __restrict__ Hb) {
    int t = blockIdx.x, tid = threadIdx.x;
    int l = t % L_;
    __shared__ float xs[IN_DIM_];
    if (tid < IN_DIM_) xs[tid] = x[(size_t)t * IN_DIM_ + tid];
    __syncthreads();
    float acc = in_b[tid] + pos[(size_t)l * D_ + tid];
    #pragma unroll 2
    for (int c = 0; c < IN_DIM_; ++c) acc += xs[c] * in_w[c * D_ + tid];
    Hb[(size_t)t * D_ + tid] = acc;
}

// ---------- K2: LayerNorm over D=256 ----------
__global__ __launch_bounds__(256) void ln_kernel(
        const float* __restrict__ in, const float* __restrict__ w,
        const float* __restrict__ b, float* __restrict__ out) {
    int r = blockIdx.x, tid = threadIdx.x;
    float v = in[(size_t)r * D_ + tid];
    float mean = block_sum_256(v) * (1.f / D_);
    float c = v - mean;
    float var = block_sum_256(c * c) * (1.f / D_);
    out[(size_t)r * D_ + tid] = c * rsqrtf(var + 1e-5f) * w[tid] + b[tid];
}

// ---------- K3: tiled fp32 GEMM, 64x64 tile, K-step 32, b128 fragments ----------
template<bool BIAS, bool RES>
__global__ __launch_bounds__(256) void gemm64(
        const float* __restrict__ A, const float* __restrict__ W,
        const float* __restrict__ bias, const float* __restrict__ res,
        float* __restrict__ C, int M, int N, int Kd) {
    __shared__ __align__(16) float As[32][68];   // [k][m]
    __shared__ __align__(16) float Ws[32][68];   // [k][n]
    int tid = threadIdx.x;
    int tx = tid & 15, ty = tid >> 4;
    int n0 = blockIdx.x * 64, m0 = blockIdx.y * 64;
    float acc[4][4] = {};
    for (int k0 = 0; k0 < Kd; k0 += 32) {
        {   // A tile: scalar coalesced global, transposed LDS write
            int k = tid & 31, m = tid >> 5;
            #pragma unroll
            for (int i = 0; i < 8; ++i)
                As[k][m + i * 8] = A[(size_t)(m0 + m + i * 8) * Kd + k0 + k];
        }
        {   // W tile: float4 global -> b128 LDS write
            #pragma unroll
            for (int i = 0; i < 2; ++i) {
                int idx = tid + i * 256;           // 0..511
                int k = idx >> 4, nq = idx & 15;
                int n = n0 + nq * 4;
                float4 wv;
                if (n + 3 < N) {
                    wv = *(const float4*)&W[(size_t)(k0 + k) * N + n];
                } else {
                    wv.x = (n + 0 < N) ? W[(size_t)(k0 + k) * N + n + 0] : 0.f;
                    wv.y = (n + 1 < N) ? W[(size_t)(k0 + k) * N + n + 1] : 0.f;
                    wv.z = (n + 2 < N) ? W[(size_t)(k0 + k) * N + n + 2] : 0.f;
                    wv.w = (n + 3 < N) ? W[(size_t)(k0 + k) * N + n + 3] : 0.f;
                }
                *(float4*)&Ws[k][nq * 4] = wv;
            }
        }
        __syncthreads();
        #pragma unroll
        for (int k = 0; k < 32; ++k) {
            float4 a  = *(const float4*)&As[k][ty * 4];
            float4 bb = *(const float4*)&Ws[k][tx * 4];
            acc[0][0] += a.x * bb.x; acc[0][1] += a.x * bb.y; acc[0][2] += a.x * bb.z; acc[0][3] += a.x * bb.w;
            acc[1][0] += a.y * bb.x; acc[1][1] += a.y * bb.y; acc[1][2] += a.y * bb.z; acc[1][3] += a.y * bb.w;
            acc[2][0] += a.z * bb.x; acc[2][1] += a.z * bb.y; acc[2][2] += a.z * bb.z; acc[2][3] += a.z * bb.w;
            acc[3][0] += a.w * bb.x; acc[3][1] += a.w * bb.y; acc[3][2] += a.w * bb.z; acc[3][3] += a.w * bb.w;
        }
        __syncthreads();
    }
    #pragma unroll
    for (int i = 0; i < 4; ++i) {
        int m = m0 + ty * 4 + i;
        int n = n0 + tx * 4;
        if (n + 3 < N) {
            float4 v = {acc[i][0], acc[i][1], acc[i][2], acc[i][3]};
            if (BIAS) {
                float4 bv = *(const float4*)&bias[n];
                v.x += bv.x; v.y += bv.y; v.z += bv.z; v.w += bv.w;
            }
            if (RES) {
                float4 rv = *(const float4*)&res[(size_t)m * N + n];
                v.x += rv.x; v.y += rv.y; v.z += rv.z; v.w += rv.w;
            }
            *(float4*)&C[(size_t)m * N + n] = v;
        } else {
            #pragma unroll
            for (int j = 0; j < 4; ++j) {
                int nn = n + j;
                if (nn < N) {
                    float v = acc[i][j];
                    if (BIAS) v += bias[nn];
                    if (RES) v += res[(size_t)m * N + nn];
                    C[(size_t)m * N + nn] = v;
                }
            }
        }
    }
}

// ---------- K4: causal conv K=4 + bias + silu ----------
__global__ __launch_bounds__(256) void conv_kernel(
        const float* __restrict__ ZX, const float* __restrict__ cw,
        const float* __restrict__ cb, float* __restrict__ XC) {
    int idx = blockIdx.x * 256 + threadIdx.x;
    if (idx >= NT_ * XBC_) return;
    int c = idx % XBC_;
    int t = idx / XBC_;
    int l = t % L_;
    float acc = cb[c];
    #pragma unroll
    for (int k = 0; k < K_; ++k) {
        int lp = l + k - (K_ - 1);
        if (lp >= 0)
            acc += ZX[(size_t)(t + k - (K_ - 1)) * DIP_ + DI_ + c] * cw[k * XBC_ + c];
    }
    XC[(size_t)idx] = siluf(acc);
}

// ---------- K5: dt softplus + cumsum per (b,h) ----------
__global__ __launch_bounds__(256) void dt_cumsum_kernel(
        const float* __restrict__ ZX, const float* __restrict__ dt_bias,
        const float* __restrict__ A_log, float* __restrict__ DT,
        float* __restrict__ CA) {
    int b = blockIdx.x / H_, h = blockIdx.x % H_;
    int tid = threadIdx.x;
    __shared__ float sc[256];
    float nA = -expf(A_log[h]);
    float bias = dt_bias[h];
    float carry = 0.f;
    for (int chunk = 0; chunk < L_ / 256; ++chunk) {
        int l = chunk * 256 + tid;
        size_t t = (size_t)b * L_ + l;
        float xv = ZX[t * DIP_ + DI_ + XBC_ + h] + bias;
        float dts = softplusf(xv);
        DT[t * H_ + h] = dts;
        float a = dts * nA;
        sc[tid] = a;
        __syncthreads();
        float v = a;
        for (int off = 1; off < 256; off <<= 1) {
            float add = (tid >= off) ? sc[tid - off] : 0.f;
            __syncthreads();
            v += add;
            sc[tid] = v;
            __syncthreads();
        }
        CA[t * H_ + h] = carry + v;
        carry += sc[255];
        __syncthreads();
    }
}

// ---------- K6: CB[b,t,s] = Cm[t,:].Bm[s,:], transposed LDS + b128 ----------
__global__ __launch_bounds__(256) void cb_kernel(
        const float* __restrict__ XC, float* __restrict__ CB) {
    int b = blockIdx.z;
    int t0 = blockIdx.y * 64, s0 = blockIdx.x * 64;
    if (s0 > t0 + 63) return;
    __shared__ __align__(16) float Cst[64][68];   // [n][t]
    __shared__ __align__(16) float Bst[64][68];   // [n][s]
    int tid = threadIdx.x, tx = tid & 15, ty = tid >> 4;
    {
        int dq = tid & 15, rr = tid >> 4;
        #pragma unroll
        for (int i = 0; i < 4; ++i) {
            int r2 = rr + i * 16;
            float4 cv = *(const float4*)&XC[(size_t)(b * L_ + t0 + r2) * XBC_ + DI_ + DS_ + dq * 4];
            Cst[dq * 4 + 0][r2] = cv.x; Cst[dq * 4 + 1][r2] = cv.y;
            Cst[dq * 4 + 2][r2] = cv.z; Cst[dq * 4 + 3][r2] = cv.w;
            float4 bv = *(const float4*)&XC[(size_t)(b * L_ + s0 + r2) * XBC_ + DI_ + dq * 4];
            Bst[dq * 4 + 0][r2] = bv.x; Bst[dq * 4 + 1][r2] = bv.y;
            Bst[dq * 4 + 2][r2] = bv.z; Bst[dq * 4 + 3][r2] = bv.w;
        }
    }
    __syncthreads();
    float acc[4][4] = {};
    #pragma unroll 4
    for (int n = 0; n < 64; ++n) {
        float4 a  = *(const float4*)&Cst[n][ty * 4];
        float4 bb = *(const float4*)&Bst[n][tx * 4];
        acc[0][0] += a.x * bb.x; acc[0][1] += a.x * bb.y; acc[0][2] += a.x * bb.z; acc[0][3] += a.x * bb.w;
        acc[1][0] += a.y * bb.x; acc[1][1] += a.y * bb.y; acc[1][2] += a.y * bb.z; acc[1][3] += a.y * bb.w;
        acc[2][0] += a.z * bb.x; acc[2][1] += a.z * bb.y; acc[2][2] += a.z * bb.z; acc[2][3] += a.z * bb.w;
        acc[3][0] += a.w * bb.x; acc[3][1] += a.w * bb.y; acc[3][2] += a.w * bb.z; acc[3][3] += a.w * bb.w;
    }
    #pragma unroll
    for (int i = 0; i < 4; ++i) {
        int t = t0 + ty * 4 + i;
        float4 v = {acc[i][0], acc[i][1], acc[i][2], acc[i][3]};
        *(float4*)&CB[((size_t)b * L_ + t) * L_ + s0 + tx * 4] = v;
    }
}

// ---------- K7: SSM quadratic, transposed Pt + b128 ----------
__global__ __launch_bounds__(256) void ssm_quad_kernel(
        const float* __restrict__ XC, const float* __restrict__ CB,
        const float* __restrict__ DT, const float* __restrict__ CA,
        const float* __restrict__ Dh_ptr, float* __restrict__ Y) {
    int b = blockIdx.z, h = blockIdx.y;
    int t0 = blockIdx.x * 64;
    int tid = threadIdx.x, tx = tid & 15, ty = tid >> 4;
    __shared__ __align__(16) float Pt[64][68];    // [s][t]
    __shared__ __align__(16) float Xs[64][68];    // [s][p]
    __shared__ float cat[64], cas[64], dts[64];
    if (tid < 64) cat[tid] = CA[((size_t)b * L_ + t0 + tid) * H_ + h];
    float acc[4][4] = {};
    float Dh = Dh_ptr[h];
    for (int s0 = 0; s0 <= t0; s0 += 64) {
        {
            int dq = tid & 15, rr = tid >> 4;
            #pragma unroll
            for (int i = 0; i < 4; ++i) {
                int ss = rr + i * 16;
                *(float4*)&Xs[ss][dq * 4] =
                    *(const float4*)&XC[(size_t)(b * L_ + s0 + ss) * XBC_ + h * HD_ + dq * 4];
            }
        }
        if (tid < 64) {
            cas[tid] = CA[((size_t)b * L_ + s0 + tid) * H_ + h];
            dts[tid] = DT[((size_t)b * L_ + s0 + tid) * H_ + h];
        }
        __syncthreads();
        bool diag = (s0 == t0);
        float p[4][4];
        #pragma unroll
        for (int i = 0; i < 4; ++i) {
            int t = ty * 4 + i;
            float ct = cat[t];
            float4 cbv = *(const float4*)&CB[((size_t)b * L_ + t0 + t) * L_ + s0 + tx * 4];
            float cb4[4] = {cbv.x, cbv.y, cbv.z, cbv.w};
            #pragma unroll
            for (int j = 0; j < 4; ++j) {
                int s = tx * 4 + j;
                float v = expf(ct - cas[s]) * cb4[j] * dts[s];
                if (diag && s > t) v = 0.f;
                p[i][j] = v;
            }
        }
        #pragma unroll
        for (int j = 0; j < 4; ++j) {
            float4 col = {p[0][j], p[1][j], p[2][j], p[3][j]};
            *(float4*)&Pt[tx * 4 + j][ty * 4] = col;
        }
        __syncthreads();
        #pragma unroll 4
        for (int s = 0; s < 64; ++s) {
            float4 a  = *(const float4*)&Pt[s][ty * 4];
            float4 xv = *(const float4*)&Xs[s][tx * 4];
            acc[0][0] += a.x * xv.x; acc[0][1] += a.x * xv.y; acc[0][2] += a.x * xv.z; acc[0][3] += a.x * xv.w;
            acc[1][0] += a.y * xv.x; acc[1][1] += a.y * xv.y; acc[1][2] += a.y * xv.z; acc[1][3] += a.y * xv.w;
            acc[2][0] += a.z * xv.x; acc[2][1] += a.z * xv.y; acc[2][2] += a.z * xv.z; acc[2][3] += a.z * xv.w;
            acc[3][0] += a.w * xv.x; acc[3][1] += a.w * xv.y; acc[3][2] += a.w * xv.z; acc[3][3] += a.w * xv.w;
        }
        __syncthreads();
    }
    #pragma unroll
    for (int i = 0; i < 4; ++i) {
        size_t t = (size_t)b * L_ + t0 + ty * 4 + i;
        float4 x4 = *(const float4*)&XC[t * XBC_ + h * HD_ + tx * 4];
        float4 o = {acc[i][0] + Dh * x4.x, acc[i][1] + Dh * x4.y,
                    acc[i][2] + Dh * x4.z, acc[i][3] + Dh * x4.w};
        *(float4*)&Y[t * DI_ + h * HD_ + tx * 4] = o;
    }
}

// ---------- K8: gate + RMSNorm ----------
__global__ __launch_bounds__(256) void gate_rms_kernel(
        float* __restrict__ Y, const float* __restrict__ ZX,
        const float* __restrict__ nw) {
    int r = blockIdx.x, tid = threadIdx.x;
    size_t ry = (size_t)r * DI_, rz = (size_t)r * DIP_;
    float y0 = Y[ry + tid], y1 = Y[ry + 256 + tid];
    float z0 = ZX[rz + tid], z1 = ZX[rz + 256 + tid];
    y0 *= siluf(z0);
    y1 *= siluf(z1);
    float ss = block_sum_256(y0 * y0 + y1 * y1) * (1.f / DI_);
    float s = rsqrtf(ss + 1e-5f);
    Y[ry + tid] = y0 * s * nw[tid];
    Y[ry + 256 + tid] = y1 * s * nw[256 + tid];
}

// ---------- K9: flash attention, Q-tile 32, register softmax, b128 frags ----------
__global__ __launch_bounds__(256) void attn_kernel(
        const float* __restrict__ QKV, float* __restrict__ O) {
    int b = blockIdx.z, hh = blockIdx.y;
    int t0 = blockIdx.x * 32;
    int tid = threadIdx.x, tx = tid & 15, ty = tid >> 4;   // ty 0..15
    __shared__ __align__(16) float Qt[64][34];   // [d][r], Q pre-scaled
    __shared__ __align__(16) float Kt[64][68];   // [d][s]
    __shared__ __align__(16) float Vs[64][68];   // [s][d]
    __shared__ __align__(16) float Pt[64][34];   // [s][r]
    {   // load Q transposed, scaled by 1/8
        int dq = tid & 15, r = tid >> 4;
        #pragma unroll
        for (int i = 0; i < 2; ++i) {
            int rr = r + i * 16;
            float4 v = *(const float4*)&QKV[(size_t)(b * L_ + t0 + rr) * QKVD_ + hh * AHD_ + dq * 4];
            Qt[dq * 4 + 0][rr] = v.x * 0.125f;
            Qt[dq * 4 + 1][rr] = v.y * 0.125f;
            Qt[dq * 4 + 2][rr] = v.z * 0.125f;
            Qt[dq * 4 + 3][rr] = v.w * 0.125f;
        }
    }
    float m[2], l[2], acc[2][4] = {};
    m[0] = m[1] = -INFINITY; l[0] = l[1] = 0.f;
    for (int s0 = 0; s0 < L_; s0 += 64) {
        {   // K transposed, V row-major
            int dq = tid & 15, s = tid >> 4;
            #pragma unroll
            for (int i = 0; i < 4; ++i) {
                int ss = s + i * 16;
                float4 kv = *(const float4*)&QKV[(size_t)(b * L_ + s0 + ss) * QKVD_ + D_ + hh * AHD_ + dq * 4];
                Kt[dq * 4 + 0][ss] = kv.x; Kt[dq * 4 + 1][ss] = kv.y;
                Kt[dq * 4 + 2][ss] = kv.z; Kt[dq * 4 + 3][ss] = kv.w;
                *(float4*)&Vs[ss][dq * 4] =
                    *(const float4*)&QKV[(size_t)(b * L_ + s0 + ss) * QKVD_ + 2 * D_ + hh * AHD_ + dq * 4];
            }
        }
        __syncthreads();
        float sv[2][4] = {};
        #pragma unroll 8
        for (int d = 0; d < 64; ++d) {
            float2 a  = *(const float2*)&Qt[d][ty * 2];
            float4 kk = *(const float4*)&Kt[d][tx * 4];
            sv[0][0] += a.x * kk.x; sv[0][1] += a.x * kk.y; sv[0][2] += a.x * kk.z; sv[0][3] += a.x * kk.w;
            sv[1][0] += a.y * kk.x; sv[1][1] += a.y * kk.y; sv[1][2] += a.y * kk.z; sv[1][3] += a.y * kk.w;
        }
        // register softmax: reduce across the 16-lane tx group
        #pragma unroll
        for (int i = 0; i < 2; ++i) {
            float mx = fmaxf(fmaxf(sv[i][0], sv[i][1]), fmaxf(sv[i][2], sv[i][3]));
            #pragma unroll
            for (int o = 1; o < 16; o <<= 1) mx = fmaxf(mx, __shfl_xor(mx, o, 64));
            float nm = fmaxf(m[i], mx);
            float corr = expf(m[i] - nm);
            m[i] = nm;
            float sum = 0.f;
            #pragma unroll
            for (int j = 0; j < 4; ++j) { sv[i][j] = expf(sv[i][j] - nm); sum += sv[i][j]; }
            #pragma unroll
            for (int o = 1; o < 16; o <<= 1) sum += __shfl_xor(sum, o, 64);
            l[i] = l[i] * corr + sum;
            #pragma unroll
            for (int j = 0; j < 4; ++j) acc[i][j] *= corr;
        }
        #pragma unroll
        for (int j = 0; j < 4; ++j) {
            float2 pp = {sv[0][j], sv[1][j]};
            *(float2*)&Pt[tx * 4 + j][ty * 2] = pp;
        }
        __syncthreads();
        #pragma unroll 8
        for (int s = 0; s < 64; ++s) {
            float2 pp = *(const float2*)&Pt[s][ty * 2];
            float4 vv = *(const float4*)&Vs[s][tx * 4];
            acc[0][0] += pp.x * vv.x; acc[0][1] += pp.x * vv.y; acc[0][2] += pp.x * vv.z; acc[0][3] += pp.x * vv.w;
            acc[1][0] += pp.y * vv.x; acc[1][1] += pp.y * vv.y; acc[1][2] += pp.y * vv.z; acc[1][3] += pp.y * vv.w;
        }
        __syncthreads();
    }
    #pragma unroll
    for (int i = 0; i < 2; ++i) {
        float inv = 1.f / l[i];
        size_t t = (size_t)b * L_ + t0 + ty * 2 + i;
        float4 o = {acc[i][0] * inv, acc[i][1] * inv, acc[i][2] * inv, acc[i][3] * inv};
        *(float4*)&O[t * D_ + hh * AHD_ + tx * 4] = o;
    }
}

// ---------- K10: GEGLU ----------
__global__ __launch_bounds__(256) void geglu_kernel(
        const float* __restrict__ M1, float* __restrict__ M2) {
    int idx = blockIdx.x * 256 + threadIdx.x;
    if (idx >= NT_ * DFF_) return;
    int r = idx / DFF_, c = idx % DFF_;
    float x1 = M1[(size_t)r * (2 * DFF_) + c];
    float x2 = M1[(size_t)r * (2 * DFF_) + DFF_ + c];
    float g = 0.5f * x1 * (1.f + erff(x1 * 0.70710678118f));
    M2[(size_t)idx] = g * x2;
}

// ---------- K11a/b: mean over L (two-stage) + heads ----------
__global__ __launch_bounds__(256) void head_partial_kernel(
        const float* __restrict__ LN, float* __restrict__ part) {
    int chunk = blockIdx.x, b = blockIdx.y;
    int tid = threadIdx.x;
    float s = 0.f;
    for (int l = 0; l < 64; ++l)
        s += LN[(size_t)(b * L_ + chunk * 64 + l) * D_ + tid];
    part[(size_t)(b * 16 + chunk) * D_ + tid] = s;
}

__global__ __launch_bounds__(256) void head_final_kernel(
        const float* __restrict__ part, const float* __restrict__ dir_w,
        const float* __restrict__ dir_b, const float* __restrict__ reg_w,
        const float* __restrict__ reg_b, float* __restrict__ out) {
    int b = blockIdx.x, tid = threadIdx.x;
    __shared__ float hm[256];
    float s = 0.f;
    #pragma unroll
    for (int c = 0; c < 16; ++c) s += part[(size_t)(b * 16 + c) * D_ + tid];
    hm[tid] = s * (1.f / L_);
    __syncthreads();
    if (tid < 6) {
        const float* w  = (tid < 3) ? dir_w : reg_w;
        const float* bb = (tid < 3) ? dir_b : reg_b;
        int j = (tid < 3) ? tid : tid - 3;
        float acc = bb[j];
        for (int d = 0; d < 256; ++d) acc += hm[d] * w[d * 3 + j];
        out[((tid < 3) ? 0 : 12) + b * 3 + j] = acc;
    }
}

// ---------- host ----------
static inline int cdiv(int a, int b) { return (a + b - 1) / b; }

extern "C" void kernel_launch(void* const* d_in, const int* in_sizes, int n_in,
                              void* d_out, int out_size, void* d_ws, size_t ws_size,
                              hipStream_t stream) {
    const float* x          = (const float*)d_in[0];
    const float* pos_emb    = (const float*)d_in[1];
    const float* in_w       = (const float*)d_in[2];
    const float* in_b       = (const float*)d_in[3];
    const float* ln1_w      = (const float*)d_in[4];
    const float* ln1_b      = (const float*)d_in[5];
    const float* ssm_in_w   = (const float*)d_in[6];
    const float* ssm_conv_w = (const float*)d_in[7];
    const float* ssm_conv_b = (const float*)d_in[8];
    const float* ssm_dt_bias= (const float*)d_in[9];
    const float* ssm_A_log  = (const float*)d_in[10];
    const float* ssm_Dp     = (const float*)d_in[11];
    const float* ssm_norm_w = (const float*)d_in[12];
    const float* ssm_out_w  = (const float*)d_in[13];
    const float* ln2_w      = (const float*)d_in[14];
    const float* ln2_b      = (const float*)d_in[15];
    const float* fc1_w      = (const float*)d_in[16];
    const float* fc1_b      = (const float*)d_in[17];
    const float* fc2_w      = (const float*)d_in[18];
    const float* fc2_b      = (const float*)d_in[19];
    const float* attn_ln_w  = (const float*)d_in[20];
    const float* attn_ln_b  = (const float*)d_in[21];
    const float* attn_qkv_w = (const float*)d_in[22];
    const float* attn_qkv_b = (const float*)d_in[23];
    const float* attn_out_w = (const float*)d_in[24];
    const float* attn_out_b = (const float*)d_in[25];
    const float* norm_w     = (const float*)d_in[26];
    const float* norm_b     = (const float*)d_in[27];
    const float* dir_w      = (const float*)d_in[28];
    const float* dir_b      = (const float*)d_in[29];
    const float* reg_w      = (const float*)d_in[30];
    const float* reg_b      = (const float*)d_in[31];
    float* out = (float*)d_out;
    float* ws  = (float*)d_ws;

    size_t off = 0;
    float* Hb  = ws + off; off += (size_t)NT_ * D_;
    float* LN  = ws + off; off += (size_t)NT_ * D_;
    float* ZX  = ws + off; off += (size_t)NT_ * DIP_;
    float* XC  = ws + off; off += (size_t)NT_ * XBC_;
    float* DTb = ws + off; off += (size_t)NT_ * H_;
    float* CAb = ws + off; off += (size_t)NT_ * H_;
    float* CBb = ws + off; off += (size_t)B_ * L_ * L_;
    float* Yb  = ws + off; off += (size_t)NT_ * DI_;
    float* HP  = ws + off; off += (size_t)B_ * 16 * D_;

    dim3 blk(256);

    in_proj_kernel<<<NT_, blk, 0, stream>>>(x, in_w, in_b, pos_emb, Hb);

    for (int i = 0; i < NL_; ++i) {
        // ---- Mamba2 block ----
        ln_kernel<<<NT_, blk, 0, stream>>>(Hb, ln1_w + i * D_, ln1_b + i * D_, LN);
        gemm64<false,false><<<dim3(cdiv(DIP_,64), NT_/64), blk, 0, stream>>>(
            LN, ssm_in_w + (size_t)i * D_ * DIP_, nullptr, nullptr, ZX, NT_, DIP_, D_);
        conv_kernel<<<cdiv(NT_*XBC_,256), blk, 0, stream>>>(
            ZX, ssm_conv_w + (size_t)i * K_ * XBC_, ssm_conv_b + i * XBC_, XC);
        dt_cumsum_kernel<<<B_*H_, blk, 0, stream>>>(
            ZX, ssm_dt_bias + i * H_, ssm_A_log + i * H_, DTb, CAb);
        cb_kernel<<<dim3(L_/64, L_/64, B_), blk, 0, stream>>>(XC, CBb);
        ssm_quad_kernel<<<dim3(L_/64, H_, B_), blk, 0, stream>>>(
            XC, CBb, DTb, CAb, ssm_Dp + i * H_, Yb);
        gate_rms_kernel<<<NT_, blk, 0, stream>>>(Yb, ZX, ssm_norm_w + (size_t)i * DI_);
        gemm64<false,true><<<dim3(cdiv(D_,64), NT_/64), blk, 0, stream>>>(
            Yb, ssm_out_w + (size_t)i * DI_ * D_, nullptr, Hb, Hb, NT_, D_, DI_);

        // ---- attention (odd layers) ----
        if (i % 2 == 1) {
            int j = i / 2;
            ln_kernel<<<NT_, blk, 0, stream>>>(Hb, attn_ln_w + j * D_, attn_ln_b + j * D_, LN);
            gemm64<true,false><<<dim3(cdiv(QKVD_,64), NT_/64), blk, 0, stream>>>(
                LN, attn_qkv_w + (size_t)j * D_ * QKVD_, attn_qkv_b + j * QKVD_,
                nullptr, ZX, NT_, QKVD_, D_);
            attn_kernel<<<dim3(L_/32, AH_, B_), blk, 0, stream>>>(ZX, XC);
            gemm64<true,true><<<dim3(cdiv(D_,64), NT_/64), blk, 0, stream>>>(
                XC, attn_out_w + (size_t)j * D_ * D_, attn_out_b + j * D_,
                Hb, Hb, NT_, D_, D_);
        }

        // ---- gated MLP ----
        ln_kernel<<<NT_, blk, 0, stream>>>(Hb, ln2_w + i * D_, ln2_b + i * D_, LN);
        gemm64<true,false><<<dim3(cdiv(2*DFF_,64), NT_/64), blk, 0, stream>>>(
            LN, fc1_w + (size_t)i * D_ * 2 * DFF_, fc1_b + i * 2 * DFF_,
            nullptr, ZX, NT_, 2 * DFF_, D_);
        geglu_kernel<<<cdiv(NT_*DFF_,256), blk, 0, stream>>>(ZX, XC);
        gemm64<true,true><<<dim3(cdiv(D_,64), NT_/64), blk, 0, stream>>>(
            XC, fc2_w + (size_t)i * DFF_ * D_, fc2_b + i * D_,
            Hb, Hb, NT_, D_, DFF_);
    }

    ln_kernel<<<NT_, blk, 0, stream>>>(Hb, norm_w, norm_b, LN);
    head_partial_kernel<<<dim3(16, B_), blk, 0, stream>>>(LN, HP);
    head_final_kernel<<<B_, blk, 0, stream>>>(HP, dir_w, dir_b, reg_w, reg_b, out);
}